// Round 10
// baseline (123.361 us; speedup 1.0000x reference)
//
#include <hip/hip_runtime.h>
#include <math.h>

// LRU (Laguerre ladder) recurrence, MI355X — two-pass checkpoint/recompute v2.
// B=32, T=512, I=64, F=64, H=64. Output: (B,T,F,H) f32 ++ h_final (F,B,H) f32.
//
// Pass 1 (2048 blocks x 64 thr, NO LDS): wave=(b,f), lane=h, r6-verified skew
// recurrence. Captures checkpoints y[16c-1][h] (c=1..31) via 4-lane predicated
// stores into ws_ck[b][c][f][h]; stores u as [b][t][f]; writes h_final.
// Pass 2 (1024 blocks x 64 thr): block=(b,c), lane=f. Seeds h[0..63] from
// ws_ck, recomputes rows t=16c..16c+15 (pure per-lane serial FMA, no cross-
// lane ops), transposes each 16KB row through swizzled LDS (conflict-free at
// the b128 floor), stores 16x 1KB sequential -> each wave writes a strictly
// sequential 256KB run (fillBuffer-shaped write stream).
#define TT 512
#define FF 64
#define BB 32
#define HH 64

__device__ __forceinline__ float shift_up1(float v, int j16) {
    // lane l gets lane l-1's value across the whole wave
    int s1 = __builtin_amdgcn_update_dpp(0, __float_as_int(v), 0x111, 0xf, 0xf, true);  // row_shr:1
    int s2 = __builtin_amdgcn_update_dpp(0, __float_as_int(v), 0x142, 0xf, 0xf, false); // row_bcast:15
    return __int_as_float((j16 == 0) ? s2 : s1);
}

// ======================= PASS 1 =======================
// One step at global index K (compile-time). Checkpoint capture: lane l holds
// y[t][l] with t=K-l; capture when t%16==15 && t<=495 -> lanes j16==(K+1)&15,
// ranged by l for the ramp edges. c = ((K+1)>>4) - (l>>4); ckl pre-subtracts
// (l>>4)*4096 so the store index is a compile-time multiple of 4096.
#define P1STEP(K, MASKED, UK) do {                                     \
    const float shifted_ = shift_up1(vlast, j16);                      \
    const float nbr_cur_ = isl0 ? (UK) : shifted_;                     \
    float v_ = fmaf(cA, nbr_cur_, fmaf(a, prev, -nbr_prev));           \
    if (MASKED) {                                                      \
        const bool live_ = ((unsigned)t < (unsigned)TT);               \
        v_ = live_ ? v_ : prev;                                        \
    }                                                                  \
    if ((K) >= 15 && (K) <= 558) {                                     \
        bool cap_ = (j16 == (((K) + 1) & 15));                         \
        if ((K) < 79)  cap_ = cap_ && (l <= (K) - 15);                 \
        if ((K) > 495) cap_ = cap_ && (l >= (K) - 495);                \
        if (cap_) ckl[(((K) + 1) >> 4) * 4096] = v_;                   \
    }                                                                  \
    nbr_prev = isl0 ? 0.f : nbr_cur_;                                  \
    prev = v_; vlast = v_;                                             \
    ++t;                                                               \
} while (0)

#define P1HALF(BASE, UREG, MASKED) do {                                \
    _Pragma("unroll")                                                  \
    for (int i_ = 0; i_ < 32; ++i_) {                                  \
        const float uk_ = __int_as_float(__builtin_amdgcn_readlane(    \
            __float_as_int(UREG), (((BASE) & 63) + i_)));              \
        P1STEP((BASE) + i_, MASKED, uk_);                              \
    }                                                                  \
} while (0)

__global__ __launch_bounds__(64) void lru_pass1(
    const float* __restrict__ x,      // (B,T,I)
    const float* __restrict__ W,      // (F,I)
    const float* __restrict__ relax,  // (F,)
    float* __restrict__ out,          // h_final section written here
    float* __restrict__ ws_u,         // (B,T,F) u
    float* __restrict__ ws_ck)        // (B,32,F,H) checkpoints y[16c-1]
{
    const int w = blockIdx.x;             // 2048: (b,f)
    const int b = w >> 6;
    const int f = w & 63;
    const int l = threadIdx.x;            // hidden index
    const int j16 = l & 15;

    // ---- u GEMM (r6-verified): ua[c] = u[t=c*64+l] ----
    float ua[8];
    {
        const float4* __restrict__ Wv = reinterpret_cast<const float4*>(W) + (size_t)f * 16;
        float4 wreg[16];
        #pragma unroll
        for (int q = 0; q < 16; ++q) wreg[q] = Wv[q];
        const float4* __restrict__ xb = reinterpret_cast<const float4*>(x) + (size_t)b * TT * 16;
        #pragma unroll
        for (int c = 0; c < 8; ++c) {
            const int tt = (c << 6) + l;
            const float4* xv = xb + (size_t)tt * 16;
            float acc = 0.f;
            #pragma unroll
            for (int q = 0; q < 16; ++q) {
                const float4 xq = xv[q], wq = wreg[q];
                acc = fmaf(xq.x, wq.x, fmaf(xq.y, wq.y, fmaf(xq.z, wq.z, fmaf(xq.w, wq.w, acc))));
            }
            ua[c] = acc;
        }
    }

    // ---- u scatter store, layout [b][t][f] ----
    {
        float* uw = ws_u + (size_t)b * (TT * FF) + (size_t)l * FF + f;
        #pragma unroll
        for (int c = 0; c < 8; ++c) uw[(size_t)c * 64 * FF] = ua[c];
    }

    // ---- skewed recurrence with checkpoint capture ----
    const float rel = relax[f];
    const float a  = sqrtf(rel);
    const float gn = sqrtf(1.0f - rel);
    const bool isl0 = (l == 0);
    const float cA = isl0 ? gn : a;

    float prev = 0.f, nbr_prev = 0.f, vlast = 0.f;
    int t = -l;
    // per-lane checkpoint base: [b][.][f][l] with the (l>>4)*4096 pre-subtracted
    float* ckl = ws_ck + (size_t)b * 131072 + (size_t)f * 64 + l - ((size_t)(l >> 4)) * 4096;

    P1HALF(0,   ua[0], true);  P1HALF(32,  ua[0], true);
    P1HALF(64,  ua[1], false); P1HALF(96,  ua[1], false);
    P1HALF(128, ua[2], false); P1HALF(160, ua[2], false);
    P1HALF(192, ua[3], false); P1HALF(224, ua[3], false);
    P1HALF(256, ua[4], false); P1HALF(288, ua[4], false);
    P1HALF(320, ua[5], false); P1HALF(352, ua[5], false);
    P1HALF(384, ua[6], false); P1HALF(416, ua[6], false);
    P1HALF(448, ua[7], false); P1HALF(480, ua[7], false);
    P1HALF(512, ua[7], true);  P1HALF(544, ua[7], true);

    // h_final = y[T-1][l] (frozen in prev)
    out[(size_t)BB * TT * FF * HH + ((size_t)f * BB + b) * HH + l] = prev;
}

// ======================= PASS 2 =======================
__global__ __launch_bounds__(64) void lru_pass2(
    const float* __restrict__ ws_u,   // (B,T,F)
    const float* __restrict__ ws_ck,  // (B,32,F,H)
    const float* __restrict__ relax,
    float* __restrict__ out)
{
    __shared__ float buf[2][4096];        // 2 x 16KB row ping-pong

    const int bid = blockIdx.x;           // 1024: (b,c)
    const int b = bid >> 5;
    const int c = bid & 31;
    const int f = threadIdx.x;            // lane = filterbank

    const float rel = relax[f];
    const float a  = sqrtf(rel);
    const float gn = sqrtf(1.0f - rel);

    // seeds: h = y[16c-1][f][0..63] (zeros for c==0)
    float h[64];
    if (c == 0) {
        #pragma unroll
        for (int i = 0; i < 64; ++i) h[i] = 0.f;
    } else {
        const float4* sp = reinterpret_cast<const float4*>(
            ws_ck + (size_t)b * 131072 + (size_t)c * 4096 + (size_t)f * 64);
        #pragma unroll
        for (int m = 0; m < 16; ++m) {
            const float4 v = sp[m];
            h[4*m] = v.x; h[4*m+1] = v.y; h[4*m+2] = v.z; h[4*m+3] = v.w;
        }
    }

    // u for the 16 rows (coalesced per row)
    float uu[16];
    {
        const float* up = ws_u + (size_t)b * (TT * FF) + (size_t)(c * 16) * FF + f;
        #pragma unroll
        for (int r = 0; r < 16; ++r) uu[r] = up[(size_t)r * FF];
    }

    // out row base (bytes): row (b, t=16c+r) = ((b*512 + 16c + r) * 4096 floats)
    char* rowOut = (char*)(out + ((size_t)b * TT + (size_t)c * 16) * (FF * HH));

    #pragma unroll
    for (int r = 0; r < 16; ++r) {
        // ---- recurrence row t = 16c + r (per-lane serial, bit-identical order) ----
        float prev_new = fmaf(gn, uu[r], fmaf(a, h[0], -0.0f));
        float old_im1 = h[0];
        h[0] = prev_new;
        #pragma unroll
        for (int i = 1; i < 64; ++i) {
            const float nw = fmaf(a, prev_new, fmaf(a, h[i], -old_im1));
            old_im1 = h[i];
            h[i] = nw;
            prev_new = nw;
        }
        // ---- swizzled LDS write: lane f, chunk m -> col ((m+f)&15) ----
        {
            char* bp = (char*)buf[r & 1];
            #pragma unroll
            for (int m = 0; m < 16; ++m) {
                float4 v; v.x = h[4*m]; v.y = h[4*m+1]; v.z = h[4*m+2]; v.w = h[4*m+3];
                *(float4*)(bp + f * 256 + (((m + f) & 15) << 4)) = v;
            }
        }
        // ---- coalesced readback + sequential 1KB stores ----
        {
            const char* bp = (const char*)buf[r & 1];
            #pragma unroll
            for (int i = 0; i < 16; ++i) {
                const int fr = i * 4 + (f >> 4);
                const int cr = f & 15;
                const float4 q = *(const float4*)(bp + fr * 256 + (((cr + fr) & 15) << 4));
                *(float4*)(rowOut + i * 1024 + f * 16) = q;
            }
        }
        rowOut += 16384;
    }
}

// ======================= FALLBACK (r6, verified 81.6us) =======================
#define NSLOT 96
#define RSF 64
#define STEP(MASKED, UK) do {                                          \
    const float shifted_ = shift_up1(vlast, j16);                      \
    const float nbr_cur_ = isj0 ? (UK) : shifted_;                     \
    float v_ = fmaf(cA, nbr_cur_, fmaf(a, prev, -nbr_prev));           \
    if (MASKED) {                                                      \
        const bool live_ = ((unsigned)t < (unsigned)TT);               \
        v_ = live_ ? v_ : prev;                                        \
        if (live_) *(float*)((char*)ring + vaddr) = v_;                \
    } else {                                                           \
        *(float*)((char*)ring + vaddr) = v_;                           \
    }                                                                  \
    vaddr += 256; vaddr = (vaddr == vtop) ? vbase : vaddr;             \
    nbr_prev = isj0 ? 0.f : nbr_cur_;                                  \
    prev = v_; vlast = v_;                                             \
    ++t;                                                               \
} while (0)
#define READS(G0, G1, G2, G3, OPP) do {                                \
    const float* rp_ = ring + (sb + (l >> 4)) * RSF + (j16 << 2);      \
    G0 = *(const float4*)(rp_ + 0 * 4 * RSF);                          \
    G1 = *(const float4*)(rp_ + 1 * 4 * RSF);                          \
    G2 = *(const float4*)(rp_ + 2 * 4 * RSF);                          \
    G3 = *(const float4*)(rp_ + 3 * 4 * RSF);                          \
    OPP = ochunk + ((size_t)(l >> 4) << 12) + (j16 << 2);              \
    ochunk += 16 * 4096;                                               \
    sb += 16; if (sb == NSLOT) sb = 0;                                 \
} while (0)
#define STORES(G0, G1, G2, G3, OPP) do {                               \
    *(float4*)(OPP + (size_t)0 * 16384) = G0;                          \
    *(float4*)(OPP + (size_t)1 * 16384) = G1;                          \
    *(float4*)(OPP + (size_t)2 * 16384) = G2;                          \
    *(float4*)(OPP + (size_t)3 * 16384) = G3;                          \
} while (0)
#define PT_RD_A do { READS(gA0,gA1,gA2,gA3, opA); } while (0)
#define PT_AB   do { STORES(gA0,gA1,gA2,gA3, opA); READS(gB0,gB1,gB2,gB3, opB); } while (0)
#define PT_BA   do { STORES(gB0,gB1,gB2,gB3, opB); READS(gA0,gA1,gA2,gA3, opA); } while (0)
#define NOPT    do {} while (0)
#define HALF(UREG, HS, MASKED, P6, P22) do {                           \
    _Pragma("unroll")                                                  \
    for (int i_ = 0; i_ < 32; ++i_) {                                  \
        const float uk_ = __int_as_float(                              \
            __builtin_amdgcn_readlane(__float_as_int(UREG), (HS) * 32 + i_)); \
        STEP(MASKED, uk_);                                             \
        if (i_ == 6)  { P6; }                                          \
        if (i_ == 22) { P22; }                                         \
    }                                                                  \
} while (0)
#define PAIR_STEADY(UREG) do {                                         \
    HALF(UREG, 0, false, PT_AB, PT_BA);                                \
    HALF(UREG, 1, false, PT_AB, PT_BA);                                \
} while (0)

__global__ __launch_bounds__(64) void lru_fallback(
    const float* __restrict__ x, const float* __restrict__ W,
    const float* __restrict__ relax, float* __restrict__ out)
{
    __shared__ float ring[NSLOT * RSF];
    const int w = blockIdx.x;
    const int b = w >> 6;
    const int f = w & 63;
    const int l = threadIdx.x;
    const int j16 = l & 15;
    float ua[8];
    {
        const float4* __restrict__ Wv = reinterpret_cast<const float4*>(W) + (size_t)f * 16;
        float4 wreg[16];
        #pragma unroll
        for (int q = 0; q < 16; ++q) wreg[q] = Wv[q];
        const float4* __restrict__ xb = reinterpret_cast<const float4*>(x) + (size_t)b * TT * 16;
        #pragma unroll
        for (int c = 0; c < 8; ++c) {
            const int tt = (c << 6) + l;
            const float4* xv = xb + (size_t)tt * 16;
            float acc = 0.f;
            #pragma unroll
            for (int q = 0; q < 16; ++q) {
                const float4 xq = xv[q], wq = wreg[q];
                acc = fmaf(xq.x, wq.x, fmaf(xq.y, wq.y, fmaf(xq.z, wq.z, fmaf(xq.w, wq.w, acc))));
            }
            ua[c] = acc;
        }
    }
    const float rel = relax[f];
    const float a  = sqrtf(rel);
    const float gn = sqrtf(1.0f - rel);
    const bool isj0 = (l == 0);
    const float cA = isj0 ? gn : a;
    float prev = 0.f, nbr_prev = 0.f, vlast = 0.f;
    int t = -l;
    const int vbase = l << 2;
    const int vtop  = NSLOT * 256 + vbase;
    int vaddr = ((NSLOT - l) % NSLOT) * 256 + vbase;
    int sb = 0;
    float* ochunk = out + (size_t)b * (TT * FF * HH) + (size_t)f * HH;
    float4 gA0, gA1, gA2, gA3, gB0, gB1, gB2, gB3;
    float *opA = nullptr, *opB = nullptr;
    HALF(ua[0], 0, true, NOPT, NOPT);
    HALF(ua[0], 1, true, NOPT, NOPT);
    HALF(ua[1], 0, false, NOPT, PT_RD_A);
    HALF(ua[1], 1, false, PT_AB, PT_BA);
    PAIR_STEADY(ua[2]);
    PAIR_STEADY(ua[3]);
    PAIR_STEADY(ua[4]);
    PAIR_STEADY(ua[5]);
    PAIR_STEADY(ua[6]);
    PAIR_STEADY(ua[7]);
    HALF(ua[7], 0, true, PT_AB, PT_BA);
    HALF(ua[7], 1, true, PT_AB, PT_BA);
    STORES(gA0, gA1, gA2, gA3, opA);
    READS(gB0, gB1, gB2, gB3, opB);
    STORES(gB0, gB1, gB2, gB3, opB);
    out[(size_t)BB * TT * FF * HH + ((size_t)f * BB + b) * HH + l] = prev;
}

extern "C" void kernel_launch(void* const* d_in, const int* in_sizes, int n_in,
                              void* d_out, int out_size, void* d_ws, size_t ws_size,
                              hipStream_t stream) {
    const float* x     = (const float*)d_in[0];
    const float* W     = (const float*)d_in[1];
    const float* relax = (const float*)d_in[2];
    float* out = (float*)d_out;
    // ws: u (B*T*F = 4MB) + checkpoints (B*32*F*H = 16MB)
    const size_t need = ((size_t)BB * TT * FF + (size_t)BB * 32 * FF * HH) * 4;
    if (ws_size >= need) {
        float* ws_u  = (float*)d_ws;
        float* ws_ck = ws_u + (size_t)BB * TT * FF;
        lru_pass1<<<dim3(2048), dim3(64), 0, stream>>>(x, W, relax, out, ws_u, ws_ck);
        lru_pass2<<<dim3(1024), dim3(64), 0, stream>>>(ws_u, ws_ck, relax, out);
    } else {
        lru_fallback<<<dim3(2048), dim3(64), 0, stream>>>(x, W, relax, out);
    }
}